// Round 1
// baseline (600.085 us; speedup 1.0000x reference)
//
#include <hip/hip_runtime.h>

// out = relu(x @ sign(W) + b)
// x: [M=8192, K=4096] f32, W: [K=4096, N=4096] f32, b: [N] f32, out: [M, N] f32
//
// Strategy:
//  1. cvt_x:  x f32 -> bf16 (RNE), into ws[0 .. M*K)
//  2. binT:   W f32 -> sign-binarized bf16 W^T [N][K], into ws[M*K .. M*K+N*K)
//  3. gemm:   bf16 MFMA 16x16x32, 128x128 tile, BK=32, global_load_lds(16B)
//             staging, fused bias+relu, f32 output.
// ws requirement: (M*K + N*K)*2 bytes = 96 MiB.

typedef __attribute__((ext_vector_type(8))) __bf16 bf16x8;
typedef __attribute__((ext_vector_type(4))) float f32x4;

#define BM 128
#define BN 128
#define BK 32

// ---------- prep 1: f32 -> bf16 (RNE), 8 elems/thread/iter ----------
__device__ __forceinline__ unsigned int bf_pack(unsigned int lo, unsigned int hi) {
    unsigned int l = (lo + 0x7FFFu + ((lo >> 16) & 1u)) >> 16;
    unsigned int h = (hi + 0x7FFFu + ((hi >> 16) & 1u)) >> 16;
    return l | (h << 16);
}

__global__ void cvt_x_kernel(const uint4* __restrict__ in, uint4* __restrict__ out, int nchunk) {
    int i = blockIdx.x * blockDim.x + threadIdx.x;
    int stride = gridDim.x * blockDim.x;
    for (; i < nchunk; i += stride) {
        uint4 a = in[2 * i];
        uint4 b = in[2 * i + 1];
        uint4 o;
        o.x = bf_pack(a.x, a.y);
        o.y = bf_pack(a.z, a.w);
        o.z = bf_pack(b.x, b.y);
        o.w = bf_pack(b.z, b.w);
        out[i] = o;
    }
}

// ---------- prep 2: binarize + transpose W -> W^T bf16 [N][K] ----------
__global__ void binT_kernel(const float* __restrict__ W, unsigned short* __restrict__ Wt,
                            int K, int N) {
    __shared__ unsigned short tile[32][33];   // +1 pad: no bank conflicts
    int tx = threadIdx.x;   // 0..31
    int ty = threadIdx.y;   // 0..7
    int k0 = blockIdx.y * 32;   // W row block
    int n0 = blockIdx.x * 32;   // W col block
    #pragma unroll
    for (int i = 0; i < 32; i += 8) {
        unsigned int u = __float_as_uint(W[(size_t)(k0 + ty + i) * N + n0 + tx]);
        // sign(W) in bf16: +1 = 0x3F80, -1 = 0xBF80  (W>=0 -> +1)
        tile[ty + i][tx] = (unsigned short)(0x3F80u | ((u >> 16) & 0x8000u));
    }
    __syncthreads();
    #pragma unroll
    for (int i = 0; i < 32; i += 8) {
        Wt[(size_t)(n0 + ty + i) * K + k0 + tx] = tile[tx][ty + i];
    }
}

// ---------- GEMM: C = A(bf16)[M][K] @ Bt(bf16)[N][K]^T, bias+relu ----------
// Block: 256 threads = 4 waves (2x2), each wave 64x64 out (4x4 frags of 16x16).
__global__ __launch_bounds__(256) void gemm_bin_kernel(
    const unsigned short* __restrict__ A,    // bf16 bits [M][K]
    const unsigned short* __restrict__ Bt,   // bf16 bits [N][K]
    const float* __restrict__ bias,
    float* __restrict__ C, int M, int N, int K)
{
    __shared__ unsigned short lda[BM * BK];  // 8 KiB
    __shared__ unsigned short ldb[BN * BK];  // 8 KiB

    const int t = threadIdx.x;
    const int w = t >> 6;        // wave 0..3
    const int l = t & 63;
    const int wm = w >> 1;       // wave row 0..1
    const int wn = w & 1;        // wave col 0..1
    const int lr = l & 15;       // frag row/col within 16
    const int lk = l >> 4;       // k-group 0..3

    const int brow = blockIdx.y * BM;
    const int bcol = blockIdx.x * BN;

    f32x4 acc[4][4] = {};

    // staging: lds element offset = r*2048 + w*512 + lane*8  (bf16 elems)
    // -> row = off/32 (tile row), col = off%32 (k within tile)
    const int soff0 = w * 512 + l * 8;

    for (int k0 = 0; k0 < K; k0 += BK) {
        __syncthreads();   // previous iter's ds_reads done before overwrite
        #pragma unroll
        for (int r = 0; r < 2; ++r) {
            int off = r * 2048 + soff0;
            int row = off >> 5, col = off & 31;
            const unsigned short* gsrc = A + (size_t)(brow + row) * K + (k0 + col);
            __builtin_amdgcn_global_load_lds(
                (const __attribute__((address_space(1))) void*)gsrc,
                (__attribute__((address_space(3))) void*)&lda[r * 2048 + w * 512],
                16, 0, 0);
        }
        #pragma unroll
        for (int r = 0; r < 2; ++r) {
            int off = r * 2048 + soff0;
            int row = off >> 5, col = off & 31;
            const unsigned short* gsrc = Bt + (size_t)(bcol + row) * K + (k0 + col);
            __builtin_amdgcn_global_load_lds(
                (const __attribute__((address_space(1))) void*)gsrc,
                (__attribute__((address_space(3))) void*)&ldb[r * 2048 + w * 512],
                16, 0, 0);
        }
        __syncthreads();   // compiler emits vmcnt(0) drain before barrier

        bf16x8 af[4], bfr[4];
        #pragma unroll
        for (int m = 0; m < 4; ++m) {
            int row = wm * 64 + m * 16 + lr;
            af[m] = *(const bf16x8*)&lda[row * BK + lk * 8];
        }
        #pragma unroll
        for (int n = 0; n < 4; ++n) {
            int col = wn * 64 + n * 16 + lr;
            bfr[n] = *(const bf16x8*)&ldb[col * BK + lk * 8];
        }
        #pragma unroll
        for (int m = 0; m < 4; ++m)
            #pragma unroll
            for (int n = 0; n < 4; ++n)
                acc[m][n] = __builtin_amdgcn_mfma_f32_16x16x32_bf16(
                    af[m], bfr[n], acc[m][n], 0, 0, 0);
    }

    // epilogue: C/D layout col = lane&15, row = (lane>>4)*4 + j  [m89-verified]
    #pragma unroll
    for (int n = 0; n < 4; ++n) {
        int col = bcol + wn * 64 + n * 16 + lr;
        float bv = bias[col];
        #pragma unroll
        for (int m = 0; m < 4; ++m) {
            #pragma unroll
            for (int j = 0; j < 4; ++j) {
                int row = brow + wm * 64 + m * 16 + lk * 4 + j;
                float v = acc[m][n][j] + bv;
                C[(size_t)row * N + col] = v > 0.f ? v : 0.f;
            }
        }
    }
}

extern "C" void kernel_launch(void* const* d_in, const int* in_sizes, int n_in,
                              void* d_out, int out_size, void* d_ws, size_t ws_size,
                              hipStream_t stream) {
    const float* x = (const float*)d_in[0];
    const float* W = (const float*)d_in[1];
    const float* b = (const float*)d_in[2];
    float* out = (float*)d_out;

    const int N = in_sizes[2];            // 4096
    const int K = in_sizes[1] / N;        // 4096
    const int M = in_sizes[0] / K;        // 8192

    unsigned short* xb = (unsigned short*)d_ws;          // [M][K] bf16
    unsigned short* wt = xb + (size_t)M * K;             // [N][K] bf16

    // 1. x -> bf16
    int nchunk = (M * K) / 8;
    cvt_x_kernel<<<2048, 256, 0, stream>>>((const uint4*)x, (uint4*)xb, nchunk);

    // 2. W -> sign-binarized bf16 transposed
    binT_kernel<<<dim3(N / 32, K / 32), dim3(32, 8), 0, stream>>>(W, wt, K, N);

    // 3. GEMM + bias + relu
    gemm_bin_kernel<<<dim3(N / BN, M / BM), 256, 0, stream>>>(xb, wt, b, out, M, N, K);
}

// Round 2
// 503.872 us; speedup vs baseline: 1.1909x; 1.1909x over previous
//
#include <hip/hip_runtime.h>

// out = relu(x @ sign(W) + b)
// x: [M=8192, K=4096] f32, W: [K=4096, N=4096] f32, b: [N] f32, out: [M, N] f32
//
// 1. cvt_x: x f32 -> bf16 (RNE) into ws
// 2. binT:  W f32 -> sign-binarized bf16 W^T [N][K] into ws
// 3. gemm8: 256x256 tile, BK=64 (two K-half buffers of [256][32]), 8 waves,
//           8-phase schedule w/ counted vmcnt(6), LDS 16B-slot XOR swizzle,
//           setprio around MFMA clusters, XCD-swizzled blockIdx,
//           fused bias+relu epilogue.

typedef __attribute__((ext_vector_type(8))) __bf16 bf16x8;
typedef __attribute__((ext_vector_type(4))) float f32x4;

#define GBM 256
#define GBN 256

#define VMW(n) do { __builtin_amdgcn_sched_barrier(0); \
    asm volatile("s_waitcnt vmcnt(" #n ")" ::: "memory"); \
    __builtin_amdgcn_sched_barrier(0); } while (0)
#define SB() do { __builtin_amdgcn_sched_barrier(0); \
    __builtin_amdgcn_s_barrier(); \
    __builtin_amdgcn_sched_barrier(0); } while (0)

// phase: ds-read frags | stage half-tile | bar | prio MFMA | counted vmcnt | bar
#define PH(buf, ks, mh, LB, STG, VN) \
    ldA(buf, ks, mh); \
    if (LB) ldB(buf, ks); \
    STG; \
    SB(); \
    __builtin_amdgcn_s_setprio(1); \
    mm(mh); \
    __builtin_amdgcn_s_setprio(0); \
    VMW(VN); \
    SB();

// ---------- prep 1: f32 -> bf16 (RNE) ----------
__device__ __forceinline__ unsigned int bf_pack(unsigned int lo, unsigned int hi) {
    unsigned int l = (lo + 0x7FFFu + ((lo >> 16) & 1u)) >> 16;
    unsigned int h = (hi + 0x7FFFu + ((hi >> 16) & 1u)) >> 16;
    return l | (h << 16);
}

__global__ void cvt_x_kernel(const uint4* __restrict__ in, uint4* __restrict__ out, int nchunk) {
    int i = blockIdx.x * blockDim.x + threadIdx.x;
    int stride = gridDim.x * blockDim.x;
    for (; i < nchunk; i += stride) {
        uint4 a = in[2 * i];
        uint4 b = in[2 * i + 1];
        uint4 o;
        o.x = bf_pack(a.x, a.y);
        o.y = bf_pack(a.z, a.w);
        o.z = bf_pack(b.x, b.y);
        o.w = bf_pack(b.z, b.w);
        out[i] = o;
    }
}

// ---------- prep 2: binarize + transpose W -> W^T bf16 [N][K] ----------
__global__ void binT_kernel(const float* __restrict__ W, unsigned short* __restrict__ Wt,
                            int K, int N) {
    __shared__ unsigned short tile[32][33];
    int tx = threadIdx.x;   // 0..31
    int ty = threadIdx.y;   // 0..7
    int k0 = blockIdx.y * 32;
    int n0 = blockIdx.x * 32;
    #pragma unroll
    for (int i = 0; i < 32; i += 8) {
        unsigned int u = __float_as_uint(W[(size_t)(k0 + ty + i) * N + n0 + tx]);
        tile[ty + i][tx] = (unsigned short)(0x3F80u | ((u >> 16) & 0x8000u));
    }
    __syncthreads();
    #pragma unroll
    for (int i = 0; i < 32; i += 8) {
        Wt[(size_t)(n0 + ty + i) * K + k0 + tx] = tile[tx][ty + i];
    }
}

// ---------- GEMM: 256^2 8-phase ----------
__global__ __launch_bounds__(512, 2) void gemm8_kernel(
    const unsigned short* __restrict__ A,    // bf16 bits [M][K]
    const unsigned short* __restrict__ Bt,   // bf16 bits [N][K]
    const float* __restrict__ bias,
    float* __restrict__ C, int M, int N, int K, int nbx)
{
    // [A|B][buf 2][ks 2][row 256][kk 32] bf16: 4*8192 elems each = 64 KiB each
    __shared__ __align__(16) unsigned short lds[65536];

    const int tid = threadIdx.x;
    const int w = tid >> 6, l = tid & 63;
    const int wm = w >> 2, wn = w & 3;       // 2 x 4 wave grid
    const int lr = l & 15, lk = l >> 4;

    // T1: bijective XCD swizzle (gridDim.x % 8 == 0)
    const int cpx = gridDim.x >> 3;
    const int wg = blockIdx.x;
    const int swz = (wg & 7) * cpx + (wg >> 3);
    const int bx = swz % nbx, by = swz / nbx;
    const int brow = by * GBM, bcol = bx * GBN;

    f32x4 acc[8][4] = {};

    // ---- staging constants (pre-swizzled GLOBAL source, linear LDS dest) ----
    // linear LDS 16B-slot (row, c16s) holds logical k-block c16s ^ ((row>>1)&3)
    const int srow0 = w * 16 + (l >> 2);                     // j=0 tile-row
    const int koff = (((l & 3) ^ ((l >> 3) & 3)) << 3);      // pre-swizzled k elems
    const unsigned short* aS[2] = {
        A  + (size_t)(brow + srow0) * K + koff,
        A  + (size_t)(brow + 128 + srow0) * K + koff };
    const unsigned short* bS[2] = {
        Bt + (size_t)(bcol + srow0) * K + koff,
        Bt + (size_t)(bcol + 128 + srow0) * K + koff };

    // ---- fragment-read constants (swizzled read) ----
    const int cswz = ((lk ^ ((lr >> 1) & 3)) << 3);
    const int aOff = (wm * 128 + lr) * 32 + cswz;
    const int bOff = (wn * 64 + lr) * 32 + cswz;

    auto stA = [&](int t, int ks) {
        int base = ((((t & 1) << 1) | ks) << 13) + w * 512;
        int kg = t * 64 + ks * 32;
        #pragma unroll
        for (int j = 0; j < 2; ++j)
            __builtin_amdgcn_global_load_lds(
                (const __attribute__((address_space(1))) void*)(aS[j] + kg),
                (__attribute__((address_space(3))) void*)&lds[base + j * 4096],
                16, 0, 0);
    };
    auto stB = [&](int t, int ks) {
        int base = 32768 + ((((t & 1) << 1) | ks) << 13) + w * 512;
        int kg = t * 64 + ks * 32;
        #pragma unroll
        for (int j = 0; j < 2; ++j)
            __builtin_amdgcn_global_load_lds(
                (const __attribute__((address_space(1))) void*)(bS[j] + kg),
                (__attribute__((address_space(3))) void*)&lds[base + j * 4096],
                16, 0, 0);
    };

    bf16x8 af[4], bf[4];
    auto ldA = [&](int buf, int ks, int mh) {
        int base = (((buf << 1) | ks) << 13) + mh * 64 * 32 + aOff;
        #pragma unroll
        for (int fm = 0; fm < 4; ++fm)
            af[fm] = *(const bf16x8*)&lds[base + fm * 16 * 32];
    };
    auto ldB = [&](int buf, int ks) {
        int base = 32768 + (((buf << 1) | ks) << 13) + bOff;
        #pragma unroll
        for (int fn = 0; fn < 4; ++fn)
            bf[fn] = *(const bf16x8*)&lds[base + fn * 16 * 32];
    };
    auto mm = [&](int mh) {
        #pragma unroll
        for (int fm = 0; fm < 4; ++fm)
            #pragma unroll
            for (int fn = 0; fn < 4; ++fn)
                acc[mh * 4 + fm][fn] = __builtin_amdgcn_mfma_f32_16x16x32_bf16(
                    af[fm], bf[fn], acc[mh * 4 + fm][fn], 0, 0, 0);
    };

    // prologue: stage "p3..p8 of iter -1" = tile0 (4 halves) + tile1 (ks0)
    stA(0, 0); stB(0, 0); stA(0, 1); stB(0, 1); stA(1, 0); stB(1, 0);
    VMW(6); SB();

    const int NI = K >> 7;   // K/128, >= 2
    for (int i = 0; i < NI - 1; ++i) {
        int t0 = 2 * i, t1 = t0 + 1;
        PH(0, 0, 0, true,  stA(t1, 1),     6)   // p1
        PH(0, 0, 1, false, stB(t1, 1),     6)   // p2
        PH(0, 1, 1, true,  stA(t0 + 2, 0), 6)   // p3
        PH(0, 1, 0, false, stB(t0 + 2, 0), 6)   // p4
        PH(1, 0, 0, true,  stA(t0 + 2, 1), 6)   // p5
        PH(1, 0, 1, false, stB(t0 + 2, 1), 6)   // p6
        PH(1, 1, 1, true,  stA(t1 + 2, 0), 6)   // p7
        PH(1, 1, 0, false, stB(t1 + 2, 0), 6)   // p8
    }
    {   // peeled last iter: no future stages; draining counted waits
        int t1 = 2 * NI - 1;
        PH(0, 0, 0, true,  stA(t1, 1), 6)
        PH(0, 0, 1, false, stB(t1, 1), 6)
        PH(0, 1, 1, true,  (void)0,    4)
        PH(0, 1, 0, false, (void)0,    4)
        PH(1, 0, 0, true,  (void)0,    2)
        PH(1, 0, 1, false, (void)0,    0)
        PH(1, 1, 1, true,  (void)0,    0)
        PH(1, 1, 0, false, (void)0,    0)
    }

    // epilogue: C/D layout col = lane&15, row = (lane>>4)*4 + j
    #pragma unroll
    for (int fn = 0; fn < 4; ++fn) {
        int col = bcol + wn * 64 + fn * 16 + lr;
        float bv = bias[col];
        #pragma unroll
        for (int im = 0; im < 8; ++im) {
            #pragma unroll
            for (int j = 0; j < 4; ++j) {
                int row = brow + wm * 128 + im * 16 + lk * 4 + j;
                float v = acc[im][fn][j] + bv;
                C[(size_t)row * N + col] = v > 0.f ? v : 0.f;
            }
        }
    }
}

extern "C" void kernel_launch(void* const* d_in, const int* in_sizes, int n_in,
                              void* d_out, int out_size, void* d_ws, size_t ws_size,
                              hipStream_t stream) {
    const float* x = (const float*)d_in[0];
    const float* W = (const float*)d_in[1];
    const float* b = (const float*)d_in[2];
    float* out = (float*)d_out;

    const int N = in_sizes[2];            // 4096
    const int K = in_sizes[1] / N;        // 4096
    const int M = in_sizes[0] / K;        // 8192

    unsigned short* xb = (unsigned short*)d_ws;          // [M][K] bf16
    unsigned short* wt = xb + (size_t)M * K;             // [N][K] bf16

    int nchunk = (M * K) / 8;
    cvt_x_kernel<<<2048, 256, 0, stream>>>((const uint4*)x, (uint4*)xb, nchunk);

    binT_kernel<<<dim3(N / 32, K / 32), dim3(32, 8), 0, stream>>>(W, wt, K, N);

    int nbx = N / GBN;
    int nwg = (M / GBM) * nbx;   // 512, divisible by 8
    gemm8_kernel<<<nwg, 512, 0, stream>>>(xb, wt, b, out, M, N, K, nbx);
}

// Round 4
// 495.685 us; speedup vs baseline: 1.2106x; 1.0165x over previous
//
#include <hip/hip_runtime.h>

// out = relu(x @ sign(W) + b)
// x: [M=8192, K=4096] f32, W: [K=4096, N=4096] f32, b: [N] f32, out: [M, N] f32
//
// 1. cvt_x: x f32 -> bf16 (RNE) into ws
// 2. binT:  W f32 -> sign-binarized bf16 W^T [N][K] into ws
// 3. gemm8: 256x256 tile, BK=64 (two K-half buffers of [256][32]), 8 waves,
//           8-phase schedule, counted vmcnt(4) at phases 4 & 8 ONLY (m201
//           template), LDS 16B-slot XOR swizzle, setprio around MFMA,
//           XCD-swizzled blockIdx, fused bias+relu epilogue.

typedef __attribute__((ext_vector_type(8))) __bf16 bf16x8;
typedef __attribute__((ext_vector_type(4))) float f32x4;

#define GBM 256
#define GBN 256

#define VMW(n) do { __builtin_amdgcn_sched_barrier(0); \
    asm volatile("s_waitcnt vmcnt(" #n ")" ::: "memory"); \
    __builtin_amdgcn_sched_barrier(0); } while (0)
#define SB() do { __builtin_amdgcn_sched_barrier(0); \
    __builtin_amdgcn_s_barrier(); \
    __builtin_amdgcn_sched_barrier(0); } while (0)

// phase: ds-read frags | stage half-tile | bar | prio MFMA | [wait] | bar
#define PH(buf, ks, mh, LB, STG, WAITCODE) \
    ldA(buf, ks, mh); \
    if (LB) ldB(buf, ks); \
    STG; \
    SB(); \
    __builtin_amdgcn_s_setprio(1); \
    mm(mh); \
    __builtin_amdgcn_s_setprio(0); \
    WAITCODE; \
    SB();

// ---------- prep 1: f32 -> bf16 (RNE) ----------
__device__ __forceinline__ unsigned int bf_pack(unsigned int lo, unsigned int hi) {
    unsigned int l = (lo + 0x7FFFu + ((lo >> 16) & 1u)) >> 16;
    unsigned int h = (hi + 0x7FFFu + ((hi >> 16) & 1u)) >> 16;
    return l | (h << 16);
}

__global__ void cvt_x_kernel(const uint4* __restrict__ in, uint4* __restrict__ out, int nchunk) {
    int i = blockIdx.x * blockDim.x + threadIdx.x;
    int stride = gridDim.x * blockDim.x;
    for (; i < nchunk; i += stride) {
        uint4 a = in[2 * i];
        uint4 b = in[2 * i + 1];
        uint4 o;
        o.x = bf_pack(a.x, a.y);
        o.y = bf_pack(a.z, a.w);
        o.z = bf_pack(b.x, b.y);
        o.w = bf_pack(b.z, b.w);
        out[i] = o;
    }
}

// ---------- prep 2: binarize + transpose W -> W^T bf16 [N][K] ----------
__global__ void binT_kernel(const float* __restrict__ W, unsigned short* __restrict__ Wt,
                            int K, int N) {
    __shared__ unsigned short tile[32][33];
    int tx = threadIdx.x;   // 0..31
    int ty = threadIdx.y;   // 0..7
    int k0 = blockIdx.y * 32;
    int n0 = blockIdx.x * 32;
    #pragma unroll
    for (int i = 0; i < 32; i += 8) {
        unsigned int u = __float_as_uint(W[(size_t)(k0 + ty + i) * N + n0 + tx]);
        tile[ty + i][tx] = (unsigned short)(0x3F80u | ((u >> 16) & 0x8000u));
    }
    __syncthreads();
    #pragma unroll
    for (int i = 0; i < 32; i += 8) {
        Wt[(size_t)(n0 + ty + i) * K + k0 + tx] = tile[tx][ty + i];
    }
}

// ---------- GEMM: 256^2 8-phase ----------
__global__ __launch_bounds__(512, 2) void gemm8_kernel(
    const unsigned short* __restrict__ A,    // bf16 bits [M][K]
    const unsigned short* __restrict__ Bt,   // bf16 bits [N][K]
    const float* __restrict__ bias,
    float* __restrict__ C, int M, int N, int K, int nbx)
{
    // [A|B][buf 2][ks 2][row 256][kk 32] bf16: 4*8192 elems each = 64 KiB each
    __shared__ __align__(16) unsigned short lds[65536];

    const int tid = threadIdx.x;
    const int w = tid >> 6, l = tid & 63;
    const int wm = w >> 2, wn = w & 3;       // 2 x 4 wave grid
    const int lr = l & 15, lk = l >> 4;

    // T1: bijective XCD swizzle (gridDim.x % 8 == 0)
    const int cpx = gridDim.x >> 3;
    const int wg = blockIdx.x;
    const int swz = (wg & 7) * cpx + (wg >> 3);
    const int bx = swz % nbx, by = swz / nbx;
    const int brow = by * GBM, bcol = bx * GBN;

    f32x4 acc[8][4] = {};

    // ---- staging constants (pre-swizzled GLOBAL source, linear LDS dest) ----
    // linear LDS 16B-slot (row, c16s) holds logical k-block c16s ^ ((row>>1)&3)
    const int srow0 = w * 16 + (l >> 2);                     // j=0 tile-row
    const int koff = (((l & 3) ^ ((l >> 3) & 3)) << 3);      // pre-swizzled k elems
    const unsigned short* aS[2] = {
        A  + (size_t)(brow + srow0) * K + koff,
        A  + (size_t)(brow + 128 + srow0) * K + koff };
    const unsigned short* bS[2] = {
        Bt + (size_t)(bcol + srow0) * K + koff,
        Bt + (size_t)(bcol + 128 + srow0) * K + koff };

    // ---- fragment-read constants (swizzled read) ----
    const int cswz = ((lk ^ ((lr >> 1) & 3)) << 3);
    const int aOff = (wm * 128 + lr) * 32 + cswz;
    const int bOff = (wn * 64 + lr) * 32 + cswz;

    auto stA = [&](int t, int ks) {
        int base = ((((t & 1) << 1) | ks) << 13) + w * 512;
        int kg = t * 64 + ks * 32;
        #pragma unroll
        for (int j = 0; j < 2; ++j)
            __builtin_amdgcn_global_load_lds(
                (const __attribute__((address_space(1))) void*)(aS[j] + kg),
                (__attribute__((address_space(3))) void*)&lds[base + j * 4096],
                16, 0, 0);
    };
    auto stB = [&](int t, int ks) {
        int base = 32768 + ((((t & 1) << 1) | ks) << 13) + w * 512;
        int kg = t * 64 + ks * 32;
        #pragma unroll
        for (int j = 0; j < 2; ++j)
            __builtin_amdgcn_global_load_lds(
                (const __attribute__((address_space(1))) void*)(bS[j] + kg),
                (__attribute__((address_space(3))) void*)&lds[base + j * 4096],
                16, 0, 0);
    };

    bf16x8 af[4], bf[4];
    auto ldA = [&](int buf, int ks, int mh) {
        int base = (((buf << 1) | ks) << 13) + mh * 64 * 32 + aOff;
        #pragma unroll
        for (int fm = 0; fm < 4; ++fm)
            af[fm] = *(const bf16x8*)&lds[base + fm * 16 * 32];
    };
    auto ldB = [&](int buf, int ks) {
        int base = 32768 + (((buf << 1) | ks) << 13) + bOff;
        #pragma unroll
        for (int fn = 0; fn < 4; ++fn)
            bf[fn] = *(const bf16x8*)&lds[base + fn * 16 * 32];
    };
    auto mm = [&](int mh) {
        #pragma unroll
        for (int fm = 0; fm < 4; ++fm)
            #pragma unroll
            for (int fn = 0; fn < 4; ++fn)
                acc[mh * 4 + fm][fn] = __builtin_amdgcn_mfma_f32_16x16x32_bf16(
                    af[fm], bf[fn], acc[mh * 4 + fm][fn], 0, 0, 0);
    };

    // prologue: stage tile0 (4 half-stages) + tile1 ks0 (2); wait first 8 loads
    stA(0, 0); stB(0, 0); stA(0, 1); stB(0, 1); stA(1, 0); stB(1, 0);
    VMW(4); SB();

    const int NI = K >> 7;   // K/128, >= 2
    for (int i = 0; i < NI - 1; ++i) {
        int t0 = 2 * i, t1 = t0 + 1;
        PH(0, 0, 0, true,  stA(t1, 1),     (void)0)   // p1
        PH(0, 0, 1, false, stB(t1, 1),     (void)0)   // p2
        PH(0, 1, 1, true,  stA(t0 + 2, 0), (void)0)   // p3
        PH(0, 1, 0, false, stB(t0 + 2, 0), VMW(4))    // p4: guarantees prev p7,p8 + cur p1,p2
        PH(1, 0, 0, true,  stA(t0 + 2, 1), (void)0)   // p5
        PH(1, 0, 1, false, stB(t0 + 2, 1), (void)0)   // p6
        PH(1, 1, 1, true,  stA(t1 + 2, 0), (void)0)   // p7
        PH(1, 1, 0, false, stB(t1 + 2, 0), VMW(4))    // p8: guarantees cur p3..p6
    }
    {   // peeled last iter: only (t1,ks1) still to stage; single drain at p4
        int t1 = 2 * NI - 1;
        PH(0, 0, 0, true,  stA(t1, 1), (void)0)
        PH(0, 0, 1, false, stB(t1, 1), (void)0)
        PH(0, 1, 1, true,  (void)0,    (void)0)
        PH(0, 1, 0, false, (void)0,    VMW(0))
        PH(1, 0, 0, true,  (void)0,    (void)0)
        PH(1, 0, 1, false, (void)0,    (void)0)
        PH(1, 1, 1, true,  (void)0,    (void)0)
        PH(1, 1, 0, false, (void)0,    (void)0)
    }

    // epilogue: C/D layout col = lane&15, row = (lane>>4)*4 + j
    #pragma unroll
    for (int fn = 0; fn < 4; ++fn) {
        int col = bcol + wn * 64 + fn * 16 + lr;
        float bv = bias[col];
        #pragma unroll
        for (int im = 0; im < 8; ++im) {
            #pragma unroll
            for (int j = 0; j < 4; ++j) {
                int row = brow + wm * 128 + im * 16 + lk * 4 + j;
                float v = acc[im][fn][j] + bv;
                C[(size_t)row * N + col] = v > 0.f ? v : 0.f;
            }
        }
    }
}

extern "C" void kernel_launch(void* const* d_in, const int* in_sizes, int n_in,
                              void* d_out, int out_size, void* d_ws, size_t ws_size,
                              hipStream_t stream) {
    const float* x = (const float*)d_in[0];
    const float* W = (const float*)d_in[1];
    const float* b = (const float*)d_in[2];
    float* out = (float*)d_out;

    const int N = in_sizes[2];            // 4096
    const int K = in_sizes[1] / N;        // 4096
    const int M = in_sizes[0] / K;        // 8192

    unsigned short* xb = (unsigned short*)d_ws;          // [M][K] bf16
    unsigned short* wt = xb + (size_t)M * K;             // [N][K] bf16

    int nchunk = (M * K) / 8;
    cvt_x_kernel<<<2048, 256, 0, stream>>>((const uint4*)x, (uint4*)xb, nchunk);

    binT_kernel<<<dim3(N / 32, K / 32), dim3(32, 8), 0, stream>>>(W, wt, K, N);

    int nbx = N / GBN;
    int nwg = (M / GBM) * nbx;   // 512, divisible by 8
    gemm8_kernel<<<nwg, 512, 0, stream>>>(xb, wt, b, out, M, N, K, nbx);
}